// Round 1
// baseline (5761.263 us; speedup 1.0000x reference)
//
#include <hip/hip_runtime.h>

#define L_NUM 8
#define SPB   8          // samples per block
#define EPS_F 1e-5f

// w12/w22: [L][32][256] -> [L][256][32] so GEMM2 weight access is contiguous per d
__global__ void transpose_w2(const float* __restrict__ w12,
                             const float* __restrict__ w22,
                             float* __restrict__ w12T,
                             float* __restrict__ w22T) {
    int idx = blockIdx.x * 256 + threadIdx.x;     // = l*8192 + d*32 + n
    if (idx >= L_NUM * 256 * 32) return;
    int n = idx & 31;
    int d = (idx >> 5) & 255;
    int l = idx >> 13;
    int src = (l * 32 + n) * 256 + d;
    w12T[idx] = w12[src];
    w22T[idx] = w22[src];
}

// Fused GEMM1(32->256) + hardswish + GEMM2(256->32) for one row, weights uniform
__device__ __forceinline__ void mix_dloop(const float* __restrict__ w1,
                                          const float* __restrict__ bb1,
                                          const float* __restrict__ w2T,
                                          const float a[32], float acc2[32]) {
    #pragma unroll
    for (int n = 0; n < 32; ++n) acc2[n] = 0.f;
    for (int d = 0; d < 256; ++d) {
        const float* w1r = w1 + d * 32;
        float t0 = 0.f, t1 = 0.f, t2 = 0.f, t3 = 0.f;
        #pragma unroll
        for (int k = 0; k < 32; k += 4) {
            t0 += a[k + 0] * w1r[k + 0];
            t1 += a[k + 1] * w1r[k + 1];
            t2 += a[k + 2] * w1r[k + 2];
            t3 += a[k + 3] * w1r[k + 3];
        }
        float td = (t0 + t1) + (t2 + t3) + bb1[d];
        float cl = fminf(fmaxf(td + 3.f, 0.f), 6.f);   // v_med3 clamp idiom
        td = td * cl * (1.f / 6.f);                    // hardswish
        const float* w2r = w2T + d * 32;
        #pragma unroll
        for (int n = 0; n < 32; ++n) acc2[n] += td * w2r[n];
    }
}

__global__ __launch_bounds__(256, 4)
void mixer_fused(const float* __restrict__ x,
                 const float* __restrict__ conv_w, const float* __restrict__ conv_b,
                 const float* __restrict__ fc0_w,  const float* __restrict__ fc0_b,
                 const float* __restrict__ ln1_g,  const float* __restrict__ ln1_b,
                 const float* __restrict__ w11,    const float* __restrict__ b11,
                 const float* __restrict__ w12T,   const float* __restrict__ b12,
                 const float* __restrict__ ln2_g,  const float* __restrict__ ln2_b,
                 const float* __restrict__ w21,    const float* __restrict__ b21,
                 const float* __restrict__ w22T,   const float* __restrict__ b22,
                 const float* __restrict__ fc1_w,  const float* __restrict__ fc1_b,
                 const float* __restrict__ fcout_w, const float* __restrict__ fcout_b,
                 float* __restrict__ out)
{
    // h: 8 samples x [32][33] (pad -> row & column access conflict-free)
    __shared__ float smem[8448 + 1024];
    float* hS  = smem;
    float* aux = smem + 8448;          // mS[256] | rS[256] ; reused as pS[1024] in epilogue

    const int tid = threadIdx.x;
    const int s   = tid >> 5;          // sample within block (0..7)
    const int r   = tid & 31;          // row index (0..31)
    const int b   = blockIdx.x * SPB + s;

    float* hrow = hS + s * 1056 + r * 33;   // this thread's row base
    float* hcol = hS + s * 1056 + r;        // this thread's column base (stride 33)
    float* mS   = aux;                      // [8][32] row means
    float* rS   = aux + 256;                // [8][32] row rstds

    // ---------- prologue: grey = 1x1 conv over channels; h0 = grey @ fc0_w.T + fc0_b
    {
        const float cw0 = conv_w[0], cw1 = conv_w[1], cw2 = conv_w[2];
        const float cb  = conv_b[0];
        const float* xb = x + (size_t)b * 3072 + r * 32;
        float g[32];
        #pragma unroll
        for (int j = 0; j < 32; ++j)
            g[j] = cw0 * xb[j] + cw1 * xb[1024 + j] + cw2 * xb[2048 + j] + cb;
        #pragma unroll 4
        for (int j = 0; j < 32; ++j) {
            const float* wr = fc0_w + j * 32;
            float acc = fc0_b[j];
            #pragma unroll
            for (int k = 0; k < 32; ++k) acc += g[k] * wr[k];
            hrow[j] = acc;
        }
    }
    // (token stats below read only this thread's own row -> no barrier needed here)

    for (int l = 0; l < L_NUM; ++l) {
        const float* w1t = w11  + l * 8192;   // [256][32]
        const float* b1t = b11  + l * 256;
        const float* w2t = w12T + l * 8192;   // [256][32]
        const float* b2t = b12  + l * 32;
        const float* w1c = w21  + l * 8192;
        const float* b1c = b21  + l * 256;
        const float* w2c = w22T + l * 8192;
        const float* b2c = b22  + l * 32;
        const float  g1r = ln1_g[l * 32 + r];   // per-lane (indexed by j=r)
        const float  b1r = ln1_b[l * 32 + r];
        const float* g2  = ln2_g + l * 32;      // lane-uniform
        const float* b2v = ln2_b + l * 32;

        for (int rep = 0; rep < 2; ++rep) {
            // ===== token mixing: LN over rows, GEMMs over transposed view =====
            {   // row stats (own row)
                float sum = 0.f, sq = 0.f;
                #pragma unroll
                for (int k = 0; k < 32; ++k) { float v = hrow[k]; sum += v; sq += v * v; }
                float m   = sum * (1.f / 32.f);
                float var = sq * (1.f / 32.f) - m * m;
                mS[s * 32 + r] = m;
                rS[s * 32 + r] = rsqrtf(var + EPS_F);
            }
            __syncthreads();   // stats ready; also orders prior h writes vs column reads
            {   // this thread computes transposed row j=r
                float a[32];
                #pragma unroll
                for (int k = 0; k < 32; ++k) {
                    float v = hcol[k * 33];                       // h[s][k][r]
                    a[k] = (v - mS[s * 32 + k]) * rS[s * 32 + k] * g1r + b1r;
                }
                float acc2[32];
                mix_dloop(w1t, b1t, w2t, a, acc2);
                #pragma unroll
                for (int n = 0; n < 32; ++n)                      // h[s][n][r] += t2[r][n]+b12[n]
                    hcol[n * 33] += acc2[n] + b2t[n];
            }
            __syncthreads();   // column writes done before channel row reads

            // ===== channel mixing: everything row-local =====
            {
                float sum = 0.f, sq = 0.f;
                #pragma unroll
                for (int k = 0; k < 32; ++k) { float v = hrow[k]; sum += v; sq += v * v; }
                float m    = sum * (1.f / 32.f);
                float rstd = rsqrtf(sq * (1.f / 32.f) - m * m + EPS_F);
                float a[32];
                #pragma unroll
                for (int k = 0; k < 32; ++k)
                    a[k] = (hrow[k] - m) * rstd * g2[k] + b2v[k];
                float acc2[32];
                mix_dloop(w1c, b1c, w2c, a, acc2);
                #pragma unroll
                for (int k = 0; k < 32; ++k)
                    hrow[k] += acc2[k] + b2c[k];
            }
            __syncthreads();   // row writes done before next token column reads
        }
    }

    // ---------- epilogue: fc1 + hardswish + AvgPool(32) + fcout
    {
        float hr[32];
        #pragma unroll
        for (int k = 0; k < 32; ++k) hr[k] = hrow[k];
        float ps[4];
        #pragma unroll
        for (int c = 0; c < 4; ++c) {
            float acc_c = 0.f;
            for (int e2 = 0; e2 < 32; ++e2) {
                const float* wr = fc1_w + (c * 32 + e2) * 32;
                float acc = fc1_b[c * 32 + e2];
                #pragma unroll
                for (int k = 0; k < 32; ++k) acc += hr[k] * wr[k];
                float cl = fminf(fmaxf(acc + 3.f, 0.f), 6.f);
                acc_c += acc * cl * (1.f / 6.f);
            }
            ps[c] = acc_c * (1.f / 32.f);
        }
        float* pS = aux;   // stats region is dead; reuse as pooled vector [8][128]
        #pragma unroll
        for (int c = 0; c < 4; ++c) pS[s * 128 + r * 4 + c] = ps[c];
        __syncthreads();
        if (r < 10) {
            const float* wr = fcout_w + r * 128;
            const float* pv = pS + s * 128;
            float acc = fcout_b[r];
            #pragma unroll 8
            for (int m = 0; m < 128; ++m) acc += pv[m] * wr[m];
            out[(size_t)b * 10 + r] = acc;
        }
    }
}

extern "C" void kernel_launch(void* const* d_in, const int* in_sizes, int n_in,
                              void* d_out, int out_size, void* d_ws, size_t ws_size,
                              hipStream_t stream) {
    (void)in_sizes; (void)n_in; (void)out_size; (void)ws_size;
    const float* x       = (const float*)d_in[0];
    const float* conv_w  = (const float*)d_in[1];
    const float* conv_b  = (const float*)d_in[2];
    const float* fc0_w   = (const float*)d_in[3];
    const float* fc0_b   = (const float*)d_in[4];
    const float* ln1_g   = (const float*)d_in[5];
    const float* ln1_b   = (const float*)d_in[6];
    const float* w11     = (const float*)d_in[7];
    const float* b11     = (const float*)d_in[8];
    const float* w12     = (const float*)d_in[9];
    const float* b12     = (const float*)d_in[10];
    const float* ln2_g   = (const float*)d_in[11];
    const float* ln2_b   = (const float*)d_in[12];
    const float* w21     = (const float*)d_in[13];
    const float* b21     = (const float*)d_in[14];
    const float* w22     = (const float*)d_in[15];
    const float* b22     = (const float*)d_in[16];
    const float* fc1_w   = (const float*)d_in[17];
    const float* fc1_b   = (const float*)d_in[18];
    const float* fcout_w = (const float*)d_in[19];
    const float* fcout_b = (const float*)d_in[20];
    float* out = (float*)d_out;

    float* w12T = (float*)d_ws;                       // [8][256][32]
    float* w22T = w12T + L_NUM * 256 * 32;            // [8][256][32]  (512 KB total)

    transpose_w2<<<dim3(256), dim3(256), 0, stream>>>(w12, w22, w12T, w22T);
    mixer_fused<<<dim3(8192 / SPB), dim3(256), 0, stream>>>(
        x, conv_w, conv_b, fc0_w, fc0_b, ln1_g, ln1_b,
        w11, b11, w12T, b12, ln2_g, ln2_b, w21, b21, w22T, b22,
        fc1_w, fc1_b, fcout_w, fcout_b, out);
}

// Round 3
// 650.844 us; speedup vs baseline: 8.8520x; 8.8520x over previous
//
#include <hip/hip_runtime.h>
#include <hip/hip_bf16.h>

#define LNUM 8

typedef __attribute__((ext_vector_type(4))) float f32x4;
typedef __attribute__((ext_vector_type(8))) short bf16x8;

#define MFMA32(A,B,C) __builtin_amdgcn_mfma_f32_16x16x32_bf16(A,B,C,0,0,0)

__device__ __forceinline__ short f2bf(float f) {
  __hip_bfloat16 h = __float2bfloat16(f);
  return __builtin_bit_cast(short, h);
}

// ws layout per (layer,branch) lb = lay*2+br, stride 34816 B:
//   [0,16384)     w1f : 1024 slots * 16B  (GEMM1 A-frags, bf16)
//   [16384,32768) w2f : 1024 slots * 16B  (GEMM2 A-frags, bf16, k-permuted, prescaled 1/6)
//   [32768,34176) params f32: b1[256], b2[32], gamma[32], beta[32]
//
// GEMM1 A-frag: slot s = dt*64+lane; elem j = w1[dt*16 + (lane&15)][8*(lane>>4)+j]
// GEMM2 A-frag (k-permuted so k-slot 8q+j <-> d = 32t+4q+j (j<4) | 32t+16+4q+j-4 (j>=4)):
//   slot s = (t*2+nt)*64+lane; n = nt*16+(lane&15); q=(lane>>4)&3
//   elem j<4:  w2[n][32t + 4q + j] / 6
//   elem j>=4: w2[n][32t + 16 + 4q + (j-4)] / 6
__global__ void prep_weights(const float* __restrict__ w11, const float* __restrict__ b11,
                             const float* __restrict__ w12, const float* __restrict__ b12,
                             const float* __restrict__ g1,  const float* __restrict__ be1,
                             const float* __restrict__ w21, const float* __restrict__ b21,
                             const float* __restrict__ w22, const float* __restrict__ b22,
                             const float* __restrict__ g2,  const float* __restrict__ be2,
                             char* __restrict__ ws)
{
  const int lb = blockIdx.x;          // 0..15
  const int lay = lb >> 1, br = lb & 1;
  const float* w1  = (br ? w21 : w11) + lay*8192;   // [256][32]
  const float* w2  = (br ? w22 : w12) + lay*8192;   // [32][256]
  const float* bb1 = (br ? b21 : b11) + lay*256;
  const float* bb2 = (br ? b22 : b12) + lay*32;
  const float* gg  = (br ? g2  : g1 ) + lay*32;
  const float* bb  = (br ? be2 : be1) + lay*32;
  char* o = ws + (size_t)lb * 34816;
  short* w1f = (short*)o;
  short* w2f = (short*)(o + 16384);
  float* pr  = (float*)(o + 32768);
  const int t = threadIdx.x;
  #pragma unroll
  for (int i = 0; i < 4; ++i) {
    int s = t + i*256;
    int lane = s & 63;
    int row = (s >> 6)*16 + (lane & 15);
    int kb  = ((lane >> 4) & 3) * 8;
    const float* src = w1 + row*32 + kb;
    #pragma unroll
    for (int j = 0; j < 8; ++j) w1f[s*8 + j] = f2bf(src[j]);
  }
  #pragma unroll
  for (int i = 0; i < 4; ++i) {
    int s = t + i*256;
    int lane = s & 63;
    int tt = s >> 7;              // k-tile 0..7 (32 d's each)
    int nt = (s >> 6) & 1;
    int n  = nt*16 + (lane & 15);
    int qq = (lane >> 4) & 3;
    const float* src = w2 + n*256 + tt*32 + qq*4;
    short* dst = w2f + s*8;
    #pragma unroll
    for (int j = 0; j < 4; ++j) dst[j]     = f2bf(src[j]      * (1.0f/6.0f));
    #pragma unroll
    for (int j = 0; j < 4; ++j) dst[4 + j] = f2bf(src[16 + j] * (1.0f/6.0f));
  }
  pr[t] = bb1[t];
  if (t < 32)      pr[256 + t] = bb2[t];
  else if (t < 64) pr[256 + t] = gg[t - 32];
  else if (t < 96) pr[256 + t] = bb[t - 64];
}

// LDS map (65536 B static):
//   [0,16384)     w1f (staged per branch-step)
//   [16384,32768) w2f
//   [32768,65536) h: 4 waves x 2 samples x [32][32] f32, XOR-swizzled (col ^ row)
__global__ __launch_bounds__(256, 2)
void mixer_mfma(const float* __restrict__ x,
                const float* __restrict__ conv_w, const float* __restrict__ conv_b,
                const float* __restrict__ fc0_w,  const float* __restrict__ fc0_b,
                const char*  __restrict__ ws,
                const float* __restrict__ fc1_w,  const float* __restrict__ fc1_b,
                const float* __restrict__ fcout_w, const float* __restrict__ fcout_b,
                float* __restrict__ out)
{
  __shared__ char smem[65536];
  const int tid = threadIdx.x;
  const int wv  = tid >> 6;
  const int lid = tid & 63;
  const int ml  = lid & 15;
  const int q   = lid >> 4;
  const int q4  = q << 2, q8 = q << 3;
  const int sl  = lid >> 5, r = lid & 31;

  const bf16x8* w1f = (const bf16x8*)smem;            // [1024]
  const bf16x8* w2f = (const bf16x8*)(smem + 16384);  // [1024]
  float* hW = (float*)(smem + 32768) + wv*2048;       // this wave's h (2 samples)

  const size_t b0 = (size_t)blockIdx.x * 8 + (size_t)wv*2;

  // ---------------- prologue: conv 3->1 + fc0 ----------------
  {
    const size_t b = b0 + sl;
    const float* xb = x + b*3072 + r*32;
    const float cw0 = conv_w[0], cw1 = conv_w[1], cw2 = conv_w[2], cb = conv_b[0];
    float g[32];
    #pragma unroll
    for (int j4 = 0; j4 < 8; ++j4) {
      f32x4 a0 = *(const f32x4*)(xb + j4*4);
      f32x4 a1 = *(const f32x4*)(xb + 1024 + j4*4);
      f32x4 a2 = *(const f32x4*)(xb + 2048 + j4*4);
      #pragma unroll
      for (int e = 0; e < 4; ++e)
        g[j4*4+e] = cw0*a0[e] + cw1*a1[e] + cw2*a2[e] + cb;
    }
    float* hs = hW + sl*1024 + (r << 5);
    #pragma unroll 4
    for (int j = 0; j < 32; ++j) {
      const float* wr = fc0_w + j*32;
      float acc = fc0_b[j];
      #pragma unroll
      for (int k = 0; k < 32; ++k) acc += g[k]*wr[k];
      hs[j ^ r] = acc;
    }
  }

  // ---------------- 32 mixing branch-steps ----------------
  for (int lay = 0; lay < LNUM; ++lay)
  for (int rep = 0; rep < 2; ++rep)
  for (int br = 0; br < 2; ++br) {
    const char* wsb = ws + (size_t)(lay*2 + br) * 34816;
    __syncthreads();
    {   // stage 32KB of frag-packed bf16 weights
      const f32x4* src = (const f32x4*)wsb;
      f32x4* dst = (f32x4*)smem;
      #pragma unroll
      for (int i = 0; i < 8; ++i)
        dst[tid + i*256] = src[tid + i*256];
    }
    __syncthreads();

    const float* pb1 = (const float*)(wsb + 32768);
    const float* pb2 = pb1 + 256;
    const float* pg  = pb1 + 288;
    const float* pbt = pb1 + 320;

    // per-row LN stats: lane <-> (sample sl, row r)
    float myMean, myRstd;
    {
      const float* hr = hW + sl*1024 + (r << 5);
      float sum = 0.f, sq = 0.f;
      #pragma unroll
      for (int k = 0; k < 32; ++k) { float v = hr[k ^ r]; sum += v; sq += v*v; }
      myMean = sum * (1.f/32.f);
      myRstd = rsqrtf(sq*(1.f/32.f) - myMean*myMean + 1e-5f);
    }

    // GEMM1 B-fragments (activations): lane -> col m = mt*16+ml, k = 8q..8q+7
    bf16x8 b1[4];
    if (br == 0) {      // token branch: Act[m=c][k=row] = LN(h)[row][c]
      #pragma unroll
      for (int mt = 0; mt < 4; ++mt) {
        const int samp = mt >> 1;
        const int c = ((mt & 1) << 4) + ml;
        const float gamma = pg[c], beta = pbt[c];
        const float* hs = hW + samp*1024;
        #pragma unroll
        for (int i = 0; i < 8; ++i) {
          const int k = q8 + i;
          float mean = __shfl(myMean, samp*32 + k, 64);
          float rstd = __shfl(myRstd, samp*32 + k, 64);
          float v = hs[(k << 5) + (c ^ k)];
          b1[mt][i] = f2bf((v - mean) * rstd * gamma + beta);
        }
      }
    } else {            // channel branch: Act[m=row][k] = LN(h)[row][k]
      float g8[8], t8[8];
      #pragma unroll
      for (int i = 0; i < 8; ++i) { g8[i] = pg[q8+i]; t8[i] = pbt[q8+i]; }
      #pragma unroll
      for (int mt = 0; mt < 4; ++mt) {
        const int samp = mt >> 1;
        const int row = ((mt & 1) << 4) + ml;
        float mean = __shfl(myMean, samp*32 + row, 64);
        float rstd = __shfl(myRstd, samp*32 + row, 64);
        const float* hr = hW + samp*1024 + (row << 5);
        #pragma unroll
        for (int i = 0; i < 8; ++i) {
          float v = hr[(q8 + i) ^ row];
          b1[mt][i] = f2bf((v - mean) * rstd * g8[i] + t8[i]);
        }
      }
    }

    // fused GEMM1 -> hardswish -> GEMM2; d processed in pairs of 16-tiles (K=32)
    f32x4 acc2[2][4];
    {
      f32x4 i0 = *(const f32x4*)(pb2 + q4);        // C2 init = b2[n], n = nt*16+4q+rg
      f32x4 i1 = *(const f32x4*)(pb2 + 16 + q4);
      #pragma unroll
      for (int mt = 0; mt < 4; ++mt) { acc2[0][mt] = i0; acc2[1][mt] = i1; }
    }
    #pragma unroll 2
    for (int t = 0; t < 8; ++t) {
      bf16x8 a1a = w1f[(t*2 + 0)*64 + lid];                // W1 frags (d-tiles 2t, 2t+1)
      bf16x8 a1b = w1f[(t*2 + 1)*64 + lid];
      f32x4 biasa = *(const f32x4*)(pb1 + t*32 + q4);      // b1[d], d = 32t+4q+rg
      f32x4 biasb = *(const f32x4*)(pb1 + t*32 + 16 + q4);
      bf16x8 a2a = w2f[(t*2 + 0)*64 + lid];                // W2 frags (k-permuted)
      bf16x8 a2b = w2f[(t*2 + 1)*64 + lid];
      #pragma unroll
      for (int mt = 0; mt < 4; ++mt) {
        f32x4 c1a = MFMA32(a1a, b1[mt], biasa);            // C1T[d][m], d=32t+4q+rg
        f32x4 c1b = MFMA32(a1b, b1[mt], biasb);            // d=32t+16+4q+rg
        bf16x8 b2;                                          // matches W2 k-permutation
        #pragma unroll
        for (int rg = 0; rg < 4; ++rg) {
          float ta = c1a[rg], tb = c1b[rg];
          float ca = fminf(fmaxf(ta + 3.f, 0.f), 6.f);     // v_med3 clamp
          float cb2 = fminf(fmaxf(tb + 3.f, 0.f), 6.f);
          b2[rg]     = f2bf(ta * ca);                      // 1/6 folded into W2
          b2[4 + rg] = f2bf(tb * cb2);
        }
        acc2[0][mt] = MFMA32(a2a, b2, acc2[0][mt]);        // C2T[n][m] += W2[n][d]*T^T[d][m]
        acc2[1][mt] = MFMA32(a2b, b2, acc2[1][mt]);
      }
    }

    // residual RMW: token h[n][c] += C2T[n][m=c]; channel h[r][n] += C2T[n][m=r]
    #pragma unroll
    for (int mt = 0; mt < 4; ++mt) {
      const int samp = mt >> 1;
      const int cr = ((mt & 1) << 4) + ml;
      float* hs = hW + samp*1024;
      #pragma unroll
      for (int nt = 0; nt < 2; ++nt)
      #pragma unroll
      for (int rg = 0; rg < 4; ++rg) {
        const int n = (nt << 4) + q4 + rg;
        const int addr = (br == 0) ? ((n << 5) + (cr ^ n)) : ((cr << 5) + (n ^ cr));
        hs[addr] += acc2[nt][mt][rg];
      }
    }
  }

  // ---------------- epilogue: fc1 + hardswish + AvgPool(32) + fcout ----------------
  {
    const size_t b = b0 + sl;
    const float* hr = hW + sl*1024 + (r << 5);
    float hv[32];
    #pragma unroll
    for (int k = 0; k < 32; ++k) hv[k] = hr[k ^ r];
    float pooled[4];
    #pragma unroll
    for (int c = 0; c < 4; ++c) {
      float accp = 0.f;
      for (int e2 = 0; e2 < 32; ++e2) {
        const float* wr = fc1_w + (c*32 + e2)*32;
        float acc = fc1_b[c*32 + e2];
        #pragma unroll
        for (int k = 0; k < 32; ++k) acc += hv[k]*wr[k];
        float cl = fminf(fmaxf(acc + 3.f, 0.f), 6.f);
        accp += acc * cl * (1.f/6.f);
      }
      pooled[c] = accp * (1.f/32.f);
    }
    float* pf = hW + sl*1024;        // h dead; wave-private region, program-order safe
    #pragma unroll
    for (int c = 0; c < 4; ++c) pf[r*4 + c] = pooled[c];
    if (r < 10) {
      const float* pv = hW + sl*1024;
      const float* wr = fcout_w + r*128;
      float acc = fcout_b[r];
      #pragma unroll 8
      for (int m = 0; m < 128; ++m) acc += pv[m]*wr[m];
      out[b*10 + r] = acc;
    }
  }
}

extern "C" void kernel_launch(void* const* d_in, const int* in_sizes, int n_in,
                              void* d_out, int out_size, void* d_ws, size_t ws_size,
                              hipStream_t stream) {
  (void)in_sizes; (void)n_in; (void)out_size; (void)ws_size;
  const float* x       = (const float*)d_in[0];
  const float* conv_w  = (const float*)d_in[1];
  const float* conv_b  = (const float*)d_in[2];
  const float* fc0_w   = (const float*)d_in[3];
  const float* fc0_b   = (const float*)d_in[4];
  const float* ln1_g   = (const float*)d_in[5];
  const float* ln1_b   = (const float*)d_in[6];
  const float* w11     = (const float*)d_in[7];
  const float* b11     = (const float*)d_in[8];
  const float* w12     = (const float*)d_in[9];
  const float* b12     = (const float*)d_in[10];
  const float* ln2_g   = (const float*)d_in[11];
  const float* ln2_b   = (const float*)d_in[12];
  const float* w21     = (const float*)d_in[13];
  const float* b21     = (const float*)d_in[14];
  const float* w22     = (const float*)d_in[15];
  const float* b22     = (const float*)d_in[16];
  const float* fc1_w   = (const float*)d_in[17];
  const float* fc1_b   = (const float*)d_in[18];
  const float* fcout_w = (const float*)d_in[19];
  const float* fcout_b = (const float*)d_in[20];
  float* out = (float*)d_out;
  char* ws = (char*)d_ws;   // 16 * 34816 = 557056 B used

  prep_weights<<<16, 256, 0, stream>>>(w11, b11, w12, b12, ln1_g, ln1_b,
                                       w21, b21, w22, b22, ln2_g, ln2_b, ws);
  mixer_mfma<<<1024, 256, 0, stream>>>(x, conv_w, conv_b, fc0_w, fc0_b,
                                       (const char*)ws, fc1_w, fc1_b,
                                       fcout_w, fcout_b, out);
}

// Round 4
// 553.621 us; speedup vs baseline: 10.4065x; 1.1756x over previous
//
#include <hip/hip_runtime.h>
#include <hip/hip_bf16.h>

#define LNUM 8

typedef __attribute__((ext_vector_type(4))) float f32x4;
typedef __attribute__((ext_vector_type(2))) float f32x2;
typedef __attribute__((ext_vector_type(8))) short bf16x8;

#define MFMA32(A,B,C) __builtin_amdgcn_mfma_f32_16x16x32_bf16(A,B,C,0,0,0)

__device__ __forceinline__ short f2bf(float f) {
  __hip_bfloat16 h = __float2bfloat16(f);
  return __builtin_bit_cast(short, h);
}

// h swizzle: row-major [32][32] f32, 16B chunks XOR'd by row&7.
// word index for (row, col c): row*32 + ((c>>2)^(row&7))*4 + (c&3)
__device__ __forceinline__ int hws(int row, int c) {
  return (row << 5) + ((((c >> 2) ^ (row & 7)) << 2) | (c & 3));
}

// ws layout per (layer,branch) lb = lay*2+br, stride 34816 B:
//   [0,16384)     w1f : 1024 slots * 16B  (GEMM1 A-frags, bf16)
//   [16384,32768) w2f : 1024 slots * 16B  (GEMM2 A-frags, bf16, k-permuted, prescaled 1/6)
//   [32768,34176) params f32: b1[256], b2[32], gamma[32], beta[32]
__global__ void prep_weights(const float* __restrict__ w11, const float* __restrict__ b11,
                             const float* __restrict__ w12, const float* __restrict__ b12,
                             const float* __restrict__ g1,  const float* __restrict__ be1,
                             const float* __restrict__ w21, const float* __restrict__ b21,
                             const float* __restrict__ w22, const float* __restrict__ b22,
                             const float* __restrict__ g2,  const float* __restrict__ be2,
                             char* __restrict__ ws)
{
  const int lb = blockIdx.x;          // 0..15
  const int lay = lb >> 1, br = lb & 1;
  const float* w1  = (br ? w21 : w11) + lay*8192;   // [256][32]
  const float* w2  = (br ? w22 : w12) + lay*8192;   // [32][256]
  const float* bb1 = (br ? b21 : b11) + lay*256;
  const float* bb2 = (br ? b22 : b12) + lay*32;
  const float* gg  = (br ? g2  : g1 ) + lay*32;
  const float* bb  = (br ? be2 : be1) + lay*32;
  char* o = ws + (size_t)lb * 34816;
  short* w1f = (short*)o;
  short* w2f = (short*)(o + 16384);
  float* pr  = (float*)(o + 32768);
  const int t = threadIdx.x;
  // GEMM1 A-frag: slot s = dt*64+lane; elem j = w1[dt*16 + (lane&15)][8*(lane>>4)+j]
  #pragma unroll
  for (int i = 0; i < 4; ++i) {
    int s = t + i*256;
    int lane = s & 63;
    int row = (s >> 6)*16 + (lane & 15);
    int kb  = ((lane >> 4) & 3) * 8;
    const float* src = w1 + row*32 + kb;
    #pragma unroll
    for (int j = 0; j < 8; ++j) w1f[s*8 + j] = f2bf(src[j]);
  }
  // GEMM2 A-frag (k-permuted): slot s = (t*2+nt)*64+lane; n = nt*16+(lane&15); q=(lane>>4)&3
  //   elem j<4:  w2[n][32t + 4q + j] / 6 ; elem j>=4: w2[n][32t + 16 + 4q + (j-4)] / 6
  #pragma unroll
  for (int i = 0; i < 4; ++i) {
    int s = t + i*256;
    int lane = s & 63;
    int tt = s >> 7;
    int nt = (s >> 6) & 1;
    int n  = nt*16 + (lane & 15);
    int qq = (lane >> 4) & 3;
    const float* src = w2 + n*256 + tt*32 + qq*4;
    short* dst = w2f + s*8;
    #pragma unroll
    for (int j = 0; j < 4; ++j) dst[j]     = f2bf(src[j]      * (1.0f/6.0f));
    #pragma unroll
    for (int j = 0; j < 4; ++j) dst[4 + j] = f2bf(src[16 + j] * (1.0f/6.0f));
  }
  pr[t] = bb1[t];
  if (t < 32)      pr[256 + t] = bb2[t];
  else if (t < 64) pr[256 + t] = gg[t - 32];
  else if (t < 96) pr[256 + t] = bb[t - 64];
}

// Per-wave LDS: h 2 samples x 1024 f32 (chunk-swizzled) + stats 64 x (mean,rstd).
// Wave-private -> ZERO barriers in the whole kernel. Weights come straight from
// global (L1-resident: every wave reads the same 32KB per step).
__global__ __launch_bounds__(256, 4)
void mixer_mfma(const float* __restrict__ x,
                const float* __restrict__ conv_w, const float* __restrict__ conv_b,
                const float* __restrict__ fc0_w,  const float* __restrict__ fc0_b,
                const char*  __restrict__ ws,
                const float* __restrict__ fc1_w,  const float* __restrict__ fc1_b,
                const float* __restrict__ fcout_w, const float* __restrict__ fcout_b,
                float* __restrict__ out)
{
  __shared__ float smem[4 * 2176];     // 34816 B
  const int tid = threadIdx.x;
  const int wv  = tid >> 6;
  const int lid = tid & 63;
  const int ml  = lid & 15;
  const int q   = lid >> 4;
  const int q4  = q << 2, q8 = q << 3;
  const int sl  = lid >> 5, r = lid & 31;
  const int r7  = r & 7;

  float* hW  = smem + wv * 2176;       // [2][1024] swizzled h
  float* stW = hW + 2048;              // [2][32] x (mean, rstd)

  const size_t b0 = (size_t)blockIdx.x * 8 + (size_t)wv * 2;

  // ---------------- prologue: conv 3->1 + fc0 ----------------
  {
    const size_t b = b0 + sl;
    const float* xb = x + b*3072 + r*32;
    const float cw0 = conv_w[0], cw1 = conv_w[1], cw2 = conv_w[2], cb = conv_b[0];
    float g[32];
    #pragma unroll
    for (int j4 = 0; j4 < 8; ++j4) {
      f32x4 a0 = *(const f32x4*)(xb + j4*4);
      f32x4 a1 = *(const f32x4*)(xb + 1024 + j4*4);
      f32x4 a2 = *(const f32x4*)(xb + 2048 + j4*4);
      #pragma unroll
      for (int e = 0; e < 4; ++e)
        g[j4*4+e] = cw0*a0[e] + cw1*a1[e] + cw2*a2[e] + cb;
    }
    float hv[32];
    #pragma unroll 4
    for (int j = 0; j < 32; ++j) {
      const float* wr = fc0_w + j*32;
      float acc = fc0_b[j];
      #pragma unroll
      for (int k = 0; k < 32; ++k) acc += g[k]*wr[k];
      hv[j] = acc;
    }
    f32x4* hp = (f32x4*)(hW + sl*1024 + (r << 5));
    #pragma unroll
    for (int a = 0; a < 8; ++a) {
      f32x4 w;
      #pragma unroll
      for (int e = 0; e < 4; ++e) w[e] = hv[a*4 + e];
      hp[a ^ r7] = w;
    }
  }

  // ---------------- 32 mixing branch-steps, barrier-free ----------------
  for (int lay = 0; lay < LNUM; ++lay)
  for (int rep = 0; rep < 2; ++rep)
  for (int br = 0; br < 2; ++br) {
    const char* wsb = ws + (size_t)(lay*2 + br) * 34816;
    const bf16x8* w1f = (const bf16x8*)wsb;             // global, L1-hot
    const bf16x8* w2f = (const bf16x8*)(wsb + 16384);
    const float* pb1 = (const float*)(wsb + 32768);
    const float* pb2 = pb1 + 256;
    const float* pg  = pb1 + 288;
    const float* pbt = pb1 + 320;

    // per-row LN stats: lane (sl, r) owns one row; publish packed (mean,rstd)
    {
      const f32x4* hp = (const f32x4*)(hW + sl*1024 + (r << 5));
      float sum = 0.f, sq = 0.f;
      #pragma unroll
      for (int a = 0; a < 8; ++a) {
        f32x4 v = hp[a ^ r7];
        #pragma unroll
        for (int e = 0; e < 4; ++e) { sum += v[e]; sq += v[e]*v[e]; }
      }
      float m = sum * (1.f/32.f);
      float rstd = rsqrtf(sq*(1.f/32.f) - m*m + 1e-5f);
      *(f32x2*)(stW + ((sl << 5) + r)*2) = (f32x2){m, rstd};
    }

    // GEMM1 B-fragments: lane -> col m = mt*16+ml, k = 8q..8q+7
    bf16x8 b1[4];
    if (br == 0) {      // token: Act[m=c][k=row] = LN(h)[row][c]  (column reads)
      const float ga = pg[ml],  gb = pg[16 + ml];
      const float ba = pbt[ml], bb2v = pbt[16 + ml];
      #pragma unroll
      for (int i = 0; i < 8; ++i) {
        const int k = q8 + i;
        f32x2 s0 = *(const f32x2*)(stW + k*2);
        f32x2 s1 = *(const f32x2*)(stW + 64 + k*2);
        #pragma unroll
        for (int mt = 0; mt < 4; ++mt) {
          const int samp = mt >> 1;
          const int c = ((mt & 1) << 4) + ml;
          f32x2 st = samp ? s1 : s0;
          float v = hW[samp*1024 + hws(k, c)];
          float g_ = (mt & 1) ? gb : ga;
          float be = (mt & 1) ? bb2v : ba;
          b1[mt][i] = f2bf((v - st[0]) * st[1] * g_ + be);
        }
      }
    } else {            // channel: Act[m=row][k] = LN(h)[row][k]  (b128 row reads)
      f32x4 g0 = *(const f32x4*)(pg + q8);
      f32x4 g1 = *(const f32x4*)(pg + q8 + 4);
      f32x4 t0 = *(const f32x4*)(pbt + q8);
      f32x4 t1 = *(const f32x4*)(pbt + q8 + 4);
      #pragma unroll
      for (int mt = 0; mt < 4; ++mt) {
        const int samp = mt >> 1;
        const int row = ((mt & 1) << 4) + ml;
        f32x2 st = *(const f32x2*)(stW + ((samp << 5) + row)*2);
        const f32x4* hr = (const f32x4*)(hW + samp*1024 + (row << 5));
        f32x4 v0 = hr[(2*q)     ^ (row & 7)];
        f32x4 v1 = hr[(2*q + 1) ^ (row & 7)];
        #pragma unroll
        for (int e = 0; e < 4; ++e) {
          b1[mt][e]     = f2bf((v0[e] - st[0]) * st[1] * g0[e] + t0[e]);
          b1[mt][4 + e] = f2bf((v1[e] - st[0]) * st[1] * g1[e] + t1[e]);
        }
      }
    }

    // fused GEMM1 -> hardswish -> GEMM2; d in pairs of 16-tiles (K=32)
    f32x4 acc2[2][4];
    {
      f32x4 i0 = *(const f32x4*)(pb2 + q4);
      f32x4 i1 = *(const f32x4*)(pb2 + 16 + q4);
      #pragma unroll
      for (int mt = 0; mt < 4; ++mt) { acc2[0][mt] = i0; acc2[1][mt] = i1; }
    }
    #pragma unroll 2
    for (int t = 0; t < 8; ++t) {
      bf16x8 a1a = w1f[(t*2 + 0)*64 + lid];
      bf16x8 a1b = w1f[(t*2 + 1)*64 + lid];
      f32x4 biasa = *(const f32x4*)(pb1 + t*32 + q4);
      f32x4 biasb = *(const f32x4*)(pb1 + t*32 + 16 + q4);
      bf16x8 a2a = w2f[(t*2 + 0)*64 + lid];
      bf16x8 a2b = w2f[(t*2 + 1)*64 + lid];
      #pragma unroll
      for (int mt = 0; mt < 4; ++mt) {
        f32x4 c1a = MFMA32(a1a, b1[mt], biasa);           // C1T[d][m], d=32t+4q+rg
        f32x4 c1b = MFMA32(a1b, b1[mt], biasb);           // d=32t+16+4q+rg
        bf16x8 b2;
        #pragma unroll
        for (int rg = 0; rg < 4; ++rg) {
          float ta = c1a[rg], tb = c1b[rg];
          float ca  = fminf(fmaxf(ta + 3.f, 0.f), 6.f);
          float cb2 = fminf(fmaxf(tb + 3.f, 0.f), 6.f);
          b2[rg]     = f2bf(ta * ca);                     // 1/6 folded into W2
          b2[4 + rg] = f2bf(tb * cb2);
        }
        acc2[0][mt] = MFMA32(a2a, b2, acc2[0][mt]);       // C2T[n][m]
        acc2[1][mt] = MFMA32(a2b, b2, acc2[1][mt]);
      }
    }

    // residual RMW
    if (br == 0) {      // token: h[n][c] += C2T[n][m=c]   (b32, 2-way free)
      #pragma unroll
      for (int mt = 0; mt < 4; ++mt) {
        const int samp = mt >> 1;
        const int c = ((mt & 1) << 4) + ml;
        float* hs = hW + samp*1024;
        #pragma unroll
        for (int nt = 0; nt < 2; ++nt)
        #pragma unroll
        for (int rg = 0; rg < 4; ++rg) {
          const int n = (nt << 4) + q4 + rg;
          hs[hws(n, c)] += acc2[nt][mt][rg];
        }
      }
    } else {            // channel: h[row][n..n+3] += acc2 (vector b128 RMW)
      #pragma unroll
      for (int mt = 0; mt < 4; ++mt) {
        const int samp = mt >> 1;
        const int row = ((mt & 1) << 4) + ml;
        f32x4* hr = (f32x4*)(hW + samp*1024 + (row << 5));
        #pragma unroll
        for (int nt = 0; nt < 2; ++nt) {
          const int a = ((nt << 2) + q) ^ (row & 7);
          f32x4 v = hr[a];
          v += acc2[nt][mt];
          hr[a] = v;
        }
      }
    }
  }

  // ---------------- epilogue: fc1 + hardswish + AvgPool(32) + fcout ----------------
  {
    const size_t b = b0 + sl;
    float hv[32];
    {
      const f32x4* hp = (const f32x4*)(hW + sl*1024 + (r << 5));
      #pragma unroll
      for (int a = 0; a < 8; ++a) {
        f32x4 v = hp[a ^ r7];
        #pragma unroll
        for (int e = 0; e < 4; ++e) hv[a*4 + e] = v[e];
      }
    }
    float pooled[4];
    #pragma unroll
    for (int c = 0; c < 4; ++c) {
      float accp = 0.f;
      for (int e2 = 0; e2 < 32; ++e2) {
        const float* wr = fc1_w + (c*32 + e2)*32;
        float acc = fc1_b[c*32 + e2];
        #pragma unroll
        for (int k = 0; k < 32; ++k) acc += hv[k]*wr[k];
        float cl = fminf(fmaxf(acc + 3.f, 0.f), 6.f);
        accp += acc * cl * (1.f/6.f);
      }
      pooled[c] = accp * (1.f/32.f);
    }
    float* pf = hW + sl*1024;     // h dead; wave-lockstep makes this safe
    #pragma unroll
    for (int c = 0; c < 4; ++c) pf[r*4 + c] = pooled[c];
    if (r < 10) {
      const float* pv = hW + sl*1024;
      const float* wr = fcout_w + r*128;
      float acc = fcout_b[r];
      #pragma unroll 8
      for (int m = 0; m < 128; ++m) acc += pv[m]*wr[m];
      out[b*10 + r] = acc;
    }
  }
}

extern "C" void kernel_launch(void* const* d_in, const int* in_sizes, int n_in,
                              void* d_out, int out_size, void* d_ws, size_t ws_size,
                              hipStream_t stream) {
  (void)in_sizes; (void)n_in; (void)out_size; (void)ws_size;
  const float* x       = (const float*)d_in[0];
  const float* conv_w  = (const float*)d_in[1];
  const float* conv_b  = (const float*)d_in[2];
  const float* fc0_w   = (const float*)d_in[3];
  const float* fc0_b   = (const float*)d_in[4];
  const float* ln1_g   = (const float*)d_in[5];
  const float* ln1_b   = (const float*)d_in[6];
  const float* w11     = (const float*)d_in[7];
  const float* b11     = (const float*)d_in[8];
  const float* w12     = (const float*)d_in[9];
  const float* b12     = (const float*)d_in[10];
  const float* ln2_g   = (const float*)d_in[11];
  const float* ln2_b   = (const float*)d_in[12];
  const float* w21     = (const float*)d_in[13];
  const float* b21     = (const float*)d_in[14];
  const float* w22     = (const float*)d_in[15];
  const float* b22     = (const float*)d_in[16];
  const float* fc1_w   = (const float*)d_in[17];
  const float* fc1_b   = (const float*)d_in[18];
  const float* fcout_w = (const float*)d_in[19];
  const float* fcout_b = (const float*)d_in[20];
  float* out = (float*)d_out;
  char* ws = (char*)d_ws;   // 16 * 34816 = 557056 B used

  prep_weights<<<16, 256, 0, stream>>>(w11, b11, w12, b12, ln1_g, ln1_b,
                                       w21, b21, w22, b22, ln2_g, ln2_b, ws);
  mixer_mfma<<<1024, 256, 0, stream>>>(x, conv_w, conv_b, fc0_w, fc0_b,
                                       (const char*)ws, fc1_w, fc1_b,
                                       fcout_w, fcout_b, out);
}

// Round 7
// 487.215 us; speedup vs baseline: 11.8249x; 1.1363x over previous
//
#include <hip/hip_runtime.h>

#define LNUM 8

typedef __attribute__((ext_vector_type(4))) float f32x4;
typedef __attribute__((ext_vector_type(2))) float f32x2;
typedef __attribute__((ext_vector_type(8))) _Float16 f16x8;
typedef __attribute__((ext_vector_type(2))) _Float16 f16x2;

// NOTE: no __has_builtin guard — it is false in the HOST pass and would #error.
// The builtin is in the gfx950 verified list; device pass compiles it fine (cf. R3 bf16).
#define MFMAH(A,B,C) __builtin_amdgcn_mfma_f32_16x16x32_f16(A,B,C,0,0,0)

// cvt_pkrtz returns __fp16-vector; bit_cast to our _Float16 vector type
#define PKRTZ(a,b) __builtin_bit_cast(f16x2, __builtin_amdgcn_cvt_pkrtz(a,b))

__device__ __forceinline__ float hswish_clamp(float t) {   // med3(t+3,0,6)
  return __builtin_amdgcn_fmed3f(t + 3.f, 0.f, 6.f);
}

// h swizzle: row-major [32][32] f32, 16B chunks XOR'd by row&7.
// word index for (row, col c): row*32 + ((c>>2)^(row&7))*4 + (c&3)
__device__ __forceinline__ int hws(int row, int c) {
  return (row << 5) + ((((c >> 2) ^ (row & 7)) << 2) | (c & 3));
}

// ws layout per (layer,branch) lb = lay*2+br, stride 34816 B:
//   [0,16384)     w1f : 1024 slots * 16B  (GEMM1 A-frags, f16)
//   [16384,32768) w2f : 1024 slots * 16B  (GEMM2 A-frags, f16, k-permuted, prescaled 1/6)
//   [32768,34176) params f32: b1[256], b2[32], gamma[32], beta[32]
__global__ void prep_weights(const float* __restrict__ w11, const float* __restrict__ b11,
                             const float* __restrict__ w12, const float* __restrict__ b12,
                             const float* __restrict__ g1,  const float* __restrict__ be1,
                             const float* __restrict__ w21, const float* __restrict__ b21,
                             const float* __restrict__ w22, const float* __restrict__ b22,
                             const float* __restrict__ g2,  const float* __restrict__ be2,
                             char* __restrict__ ws)
{
  const int lb = blockIdx.x;          // 0..15
  const int lay = lb >> 1, br = lb & 1;
  const float* w1  = (br ? w21 : w11) + lay*8192;   // [256][32]
  const float* w2  = (br ? w22 : w12) + lay*8192;   // [32][256]
  const float* bb1 = (br ? b21 : b11) + lay*256;
  const float* bb2 = (br ? b22 : b12) + lay*32;
  const float* gg  = (br ? g2  : g1 ) + lay*32;
  const float* bb  = (br ? be2 : be1) + lay*32;
  char* o = ws + (size_t)lb * 34816;
  _Float16* w1f = (_Float16*)o;
  _Float16* w2f = (_Float16*)(o + 16384);
  float* pr  = (float*)(o + 32768);
  const int t = threadIdx.x;
  // GEMM1 A-frag: slot s = dt*64+lane; elem j = w1[dt*16 + (lane&15)][8*(lane>>4)+j]
  #pragma unroll
  for (int i = 0; i < 4; ++i) {
    int s = t + i*256;
    int lane = s & 63;
    int row = (s >> 6)*16 + (lane & 15);
    int kb  = ((lane >> 4) & 3) * 8;
    const float* src = w1 + row*32 + kb;
    #pragma unroll
    for (int j = 0; j < 8; ++j) w1f[s*8 + j] = (_Float16)src[j];
  }
  // GEMM2 A-frag (k-permuted): slot s = (t*2+nt)*64+lane; n = nt*16+(lane&15); q=(lane>>4)&3
  //   elem j<4:  w2[n][32t + 4q + j] / 6 ; elem j>=4: w2[n][32t + 16 + 4q + (j-4)] / 6
  #pragma unroll
  for (int i = 0; i < 4; ++i) {
    int s = t + i*256;
    int lane = s & 63;
    int tt = s >> 7;
    int nt = (s >> 6) & 1;
    int n  = nt*16 + (lane & 15);
    int qq = (lane >> 4) & 3;
    const float* src = w2 + n*256 + tt*32 + qq*4;
    _Float16* dst = w2f + s*8;
    #pragma unroll
    for (int j = 0; j < 4; ++j) dst[j]     = (_Float16)(src[j]      * (1.0f/6.0f));
    #pragma unroll
    for (int j = 0; j < 4; ++j) dst[4 + j] = (_Float16)(src[16 + j] * (1.0f/6.0f));
  }
  pr[t] = bb1[t];
  if (t < 32)      pr[256 + t] = bb2[t];
  else if (t < 64) pr[256 + t] = gg[t - 32];
  else if (t < 96) pr[256 + t] = bb[t - 64];
}

// Per-wave LDS: h 2 samples x 1024 f32 (chunk-swizzled) + stats 64 x (mean,rstd).
// Wave-private -> ZERO barriers. Weights straight from global (L1-hot).
__global__ __launch_bounds__(256, 4)
void mixer_mfma(const float* __restrict__ x,
                const float* __restrict__ conv_w, const float* __restrict__ conv_b,
                const float* __restrict__ fc0_w,  const float* __restrict__ fc0_b,
                const char*  __restrict__ ws,
                const float* __restrict__ fc1_w,  const float* __restrict__ fc1_b,
                const float* __restrict__ fcout_w, const float* __restrict__ fcout_b,
                float* __restrict__ out)
{
  __shared__ float smem[4 * 2176];     // 34816 B
  const int tid = threadIdx.x;
  const int wv  = tid >> 6;
  const int lid = tid & 63;
  const int ml  = lid & 15;
  const int q   = lid >> 4;
  const int q4  = q << 2, q8 = q << 3;
  const int sl  = lid >> 5, r = lid & 31;
  const int r7  = r & 7;

  float* hW  = smem + wv * 2176;       // [2][1024] swizzled h
  float* stW = hW + 2048;              // [2][32] x (mean, rstd)

  const size_t b0 = (size_t)blockIdx.x * 8 + (size_t)wv * 2;

  // ---------------- prologue: conv 3->1 + fc0 (store chunk-wise) ----------
  {
    const size_t b = b0 + sl;
    const float* xb = x + b*3072 + r*32;
    const float cw0 = conv_w[0], cw1 = conv_w[1], cw2 = conv_w[2], cb = conv_b[0];
    float g[32];
    #pragma unroll
    for (int j4 = 0; j4 < 8; ++j4) {
      f32x4 a0 = *(const f32x4*)(xb + j4*4);
      f32x4 a1 = *(const f32x4*)(xb + 1024 + j4*4);
      f32x4 a2 = *(const f32x4*)(xb + 2048 + j4*4);
      #pragma unroll
      for (int e = 0; e < 4; ++e)
        g[j4*4+e] = cw0*a0[e] + cw1*a1[e] + cw2*a2[e] + cb;
    }
    f32x4* hp = (f32x4*)(hW + sl*1024 + (r << 5));
    #pragma unroll
    for (int a = 0; a < 8; ++a) {
      f32x4 w;
      #pragma unroll
      for (int e = 0; e < 4; ++e) {
        const int j = a*4 + e;
        const float* wr = fc0_w + j*32;
        float acc = fc0_b[j];
        #pragma unroll
        for (int k = 0; k < 32; ++k) acc += g[k]*wr[k];
        w[e] = acc;
      }
      hp[a ^ r7] = w;      // store immediately -> no hv[32] spill
    }
  }

  // ---------------- 32 mixing branch-steps, barrier-free ----------------
  for (int lay = 0; lay < LNUM; ++lay)
  for (int rep = 0; rep < 2; ++rep)
  for (int br = 0; br < 2; ++br) {
    const char* wsb = ws + (size_t)(lay*2 + br) * 34816;
    const f16x8* w1f = (const f16x8*)wsb;               // global, L1-hot
    const f16x8* w2f = (const f16x8*)(wsb + 16384);
    const float* pb1 = (const float*)(wsb + 32768);
    const float* pb2 = pb1 + 256;
    const float* pg  = pb1 + 288;
    const float* pbt = pb1 + 320;

    // per-row LN stats
    {
      const f32x4* hp = (const f32x4*)(hW + sl*1024 + (r << 5));
      float sum = 0.f, sq = 0.f;
      #pragma unroll
      for (int a = 0; a < 8; ++a) {
        f32x4 v = hp[a ^ r7];
        #pragma unroll
        for (int e = 0; e < 4; ++e) { sum += v[e]; sq += v[e]*v[e]; }
      }
      float m = sum * (1.f/32.f);
      float rstd = rsqrtf(sq*(1.f/32.f) - m*m + 1e-5f);
      *(f32x2*)(stW + ((sl << 5) + r)*2) = (f32x2){m, rstd};
    }

    // GEMM1 B-fragments (f16): lane -> col m = mt*16+ml, k = 8q..8q+7
    f16x8 b1[4];
    if (br == 0) {      // token: Act[m=c][k=row] = LN(h)[row][c]  (column reads)
      const float ga = pg[ml],  gb = pg[16 + ml];
      const float ba = pbt[ml], bb2v = pbt[16 + ml];
      #pragma unroll
      for (int i = 0; i < 8; ++i) {
        const int k = q8 + i;
        f32x2 s0 = *(const f32x2*)(stW + k*2);
        f32x2 s1 = *(const f32x2*)(stW + 64 + k*2);
        #pragma unroll
        for (int mt = 0; mt < 4; ++mt) {
          const int samp = mt >> 1;
          const int c = ((mt & 1) << 4) + ml;
          f32x2 st = samp ? s1 : s0;
          float v = hW[samp*1024 + hws(k, c)];
          float g_ = (mt & 1) ? gb : ga;
          float be = (mt & 1) ? bb2v : ba;
          b1[mt][i] = (_Float16)((v - st[0]) * st[1] * g_ + be);
        }
      }
    } else {            // channel: Act[m=row][k] = LN(h)[row][k]  (b128 row reads)
      f32x4 g0 = *(const f32x4*)(pg + q8);
      f32x4 g1 = *(const f32x4*)(pg + q8 + 4);
      f32x4 t0 = *(const f32x4*)(pbt + q8);
      f32x4 t1 = *(const f32x4*)(pbt + q8 + 4);
      #pragma unroll
      for (int mt = 0; mt < 4; ++mt) {
        const int samp = mt >> 1;
        const int row = ((mt & 1) << 4) + ml;
        f32x2 st = *(const f32x2*)(stW + ((samp << 5) + row)*2);
        const f32x4* hr = (const f32x4*)(hW + samp*1024 + (row << 5));
        f32x4 v0 = hr[(2*q)     ^ (row & 7)];
        f32x4 v1 = hr[(2*q + 1) ^ (row & 7)];
        #pragma unroll
        for (int e = 0; e < 4; ++e) {
          b1[mt][e]     = (_Float16)((v0[e] - st[0]) * st[1] * g0[e] + t0[e]);
          b1[mt][4 + e] = (_Float16)((v1[e] - st[0]) * st[1] * g1[e] + t1[e]);
        }
      }
    }

    // fused GEMM1 -> hardswish -> GEMM2; d in pairs of 16-tiles (K=32)
    f32x4 acc2[2][4];
    {
      f32x4 i0 = *(const f32x4*)(pb2 + q4);
      f32x4 i1 = *(const f32x4*)(pb2 + 16 + q4);
      #pragma unroll
      for (int mt = 0; mt < 4; ++mt) { acc2[0][mt] = i0; acc2[1][mt] = i1; }
    }
    #pragma unroll 2
    for (int t = 0; t < 8; ++t) {
      f16x8 a1a = w1f[(t*2 + 0)*64 + lid];
      f16x8 a1b = w1f[(t*2 + 1)*64 + lid];
      f32x4 biasa = *(const f32x4*)(pb1 + t*32 + q4);
      f32x4 biasb = *(const f32x4*)(pb1 + t*32 + 16 + q4);
      f16x8 a2a = w2f[(t*2 + 0)*64 + lid];
      f16x8 a2b = w2f[(t*2 + 1)*64 + lid];
      #pragma unroll
      for (int mt = 0; mt < 4; ++mt) {
        f32x4 c1a = MFMAH(a1a, b1[mt], biasa);            // C1T[d][m], d=32t+4q+rg
        f32x4 c1b = MFMAH(a1b, b1[mt], biasb);            // d=32t+16+4q+rg
        float va0 = c1a[0]*hswish_clamp(c1a[0]);          // 1/6 folded into W2
        float va1 = c1a[1]*hswish_clamp(c1a[1]);
        float va2 = c1a[2]*hswish_clamp(c1a[2]);
        float va3 = c1a[3]*hswish_clamp(c1a[3]);
        float vb0 = c1b[0]*hswish_clamp(c1b[0]);
        float vb1 = c1b[1]*hswish_clamp(c1b[1]);
        float vb2 = c1b[2]*hswish_clamp(c1b[2]);
        float vb3 = c1b[3]*hswish_clamp(c1b[3]);
        union { f16x2 h2[4]; f16x8 v; } b2u;
        b2u.h2[0] = PKRTZ(va0, va1);
        b2u.h2[1] = PKRTZ(va2, va3);
        b2u.h2[2] = PKRTZ(vb0, vb1);
        b2u.h2[3] = PKRTZ(vb2, vb3);
        acc2[0][mt] = MFMAH(a2a, b2u.v, acc2[0][mt]);     // C2T[n][m]
        acc2[1][mt] = MFMAH(a2b, b2u.v, acc2[1][mt]);
      }
    }

    // residual RMW
    if (br == 0) {      // token: h[n][c] += C2T[n][m=c]   (b32, 2-way free)
      #pragma unroll
      for (int mt = 0; mt < 4; ++mt) {
        const int samp = mt >> 1;
        const int c = ((mt & 1) << 4) + ml;
        float* hs = hW + samp*1024;
        #pragma unroll
        for (int nt = 0; nt < 2; ++nt)
        #pragma unroll
        for (int rg = 0; rg < 4; ++rg) {
          const int n = (nt << 4) + q4 + rg;
          hs[hws(n, c)] += acc2[nt][mt][rg];
        }
      }
    } else {            // channel: h[row][n..n+3] += acc2 (vector b128 RMW)
      #pragma unroll
      for (int mt = 0; mt < 4; ++mt) {
        const int samp = mt >> 1;
        const int row = ((mt & 1) << 4) + ml;
        f32x4* hr = (f32x4*)(hW + samp*1024 + (row << 5));
        #pragma unroll
        for (int nt = 0; nt < 2; ++nt) {
          const int a = ((nt << 2) + q) ^ (row & 7);
          f32x4 v = hr[a];
          v += acc2[nt][mt];
          hr[a] = v;
        }
      }
    }
  }

  // ---------------- epilogue: fc1 + hardswish + AvgPool(32) + fcout ----------
  {
    const size_t b = b0 + sl;
    float hv[32];
    {
      const f32x4* hp = (const f32x4*)(hW + sl*1024 + (r << 5));
      #pragma unroll
      for (int a = 0; a < 8; ++a) {
        f32x4 v = hp[a ^ r7];
        #pragma unroll
        for (int e = 0; e < 4; ++e) hv[a*4 + e] = v[e];
      }
    }
    float pooled[4];
    #pragma unroll
    for (int c = 0; c < 4; ++c) {
      float accp = 0.f;
      for (int e2 = 0; e2 < 32; ++e2) {
        const float* wr = fc1_w + (c*32 + e2)*32;
        float acc = fc1_b[c*32 + e2];
        #pragma unroll
        for (int k = 0; k < 32; ++k) acc += hv[k]*wr[k];
        accp += acc * hswish_clamp(acc) * (1.f/6.f);
      }
      pooled[c] = accp * (1.f/32.f);
    }
    float* pf = hW + sl*1024;     // h dead; wave-lockstep makes this safe
    #pragma unroll
    for (int c = 0; c < 4; ++c) pf[r*4 + c] = pooled[c];
    if (r < 10) {
      const float* pv = hW + sl*1024;
      const float* wr = fcout_w + r*128;
      float acc = fcout_b[r];
      #pragma unroll 8
      for (int m = 0; m < 128; ++m) acc += pv[m]*wr[m];
      out[b*10 + r] = acc;
    }
  }
}

extern "C" void kernel_launch(void* const* d_in, const int* in_sizes, int n_in,
                              void* d_out, int out_size, void* d_ws, size_t ws_size,
                              hipStream_t stream) {
  (void)in_sizes; (void)n_in; (void)out_size; (void)ws_size;
  const float* x       = (const float*)d_in[0];
  const float* conv_w  = (const float*)d_in[1];
  const float* conv_b  = (const float*)d_in[2];
  const float* fc0_w   = (const float*)d_in[3];
  const float* fc0_b   = (const float*)d_in[4];
  const float* ln1_g   = (const float*)d_in[5];
  const float* ln1_b   = (const float*)d_in[6];
  const float* w11     = (const float*)d_in[7];
  const float* b11     = (const float*)d_in[8];
  const float* w12     = (const float*)d_in[9];
  const float* b12     = (const float*)d_in[10];
  const float* ln2_g   = (const float*)d_in[11];
  const float* ln2_b   = (const float*)d_in[12];
  const float* w21     = (const float*)d_in[13];
  const float* b21     = (const float*)d_in[14];
  const float* w22     = (const float*)d_in[15];
  const float* b22     = (const float*)d_in[16];
  const float* fc1_w   = (const float*)d_in[17];
  const float* fc1_b   = (const float*)d_in[18];
  const float* fcout_w = (const float*)d_in[19];
  const float* fcout_b = (const float*)d_in[20];
  float* out = (float*)d_out;
  char* ws = (char*)d_ws;   // 16 * 34816 = 557056 B used

  prep_weights<<<16, 256, 0, stream>>>(w11, b11, w12, b12, ln1_g, ln1_b,
                                       w21, b21, w22, b22, ln2_g, ln2_b, ws);
  mixer_mfma<<<1024, 256, 0, stream>>>(x, conv_w, conv_b, fc0_w, fc0_b,
                                       (const char*)ws, fc1_w, fc1_b,
                                       fcout_w, fcout_b, out);
}